// Round 2
// baseline (210.071 us; speedup 1.0000x reference)
//
#include <hip/hip_runtime.h>

#define NN 10000
#define NE 320000
#define ROW_WORDS 320   // 320*32 = 10240 bits >= 10000
#define MP 10112        // 158*64 padded rows
#define BN_EPS 1e-5f

typedef __attribute__((ext_vector_type(8))) short short8;
typedef __attribute__((ext_vector_type(4))) float f32x4;
typedef unsigned short u16;

// ---------------- helpers ----------------
__device__ __forceinline__ void split1(float v, u16& h, u16& l) {
    unsigned int u = __float_as_uint(v);
    h = (u16)(u >> 16);
    float hf = __uint_as_float(u & 0xFFFF0000u);
    l = (u16)(__float_as_uint(v - hf) >> 16);
}

__device__ __forceinline__ void gll16(const void* g, void* l) {
    __builtin_amdgcn_global_load_lds(
        (const __attribute__((address_space(1))) unsigned int*)g,
        (__attribute__((address_space(3))) unsigned int*)l, 16, 0, 0);
}

// ---------------- splitW (proven): Wt[n][k] = split(W[k][n]) ----------------
__device__ void splitW_dev(const float* __restrict__ W, int K, int N, int Kp, int Np,
                           u16* __restrict__ Wt, int bx, int by, char* smem) {
    float (*tile)[65] = (float(*)[65])smem;
    int t = threadIdx.x;
    int bk = bx * 64, bn = by * 64;
    #pragma unroll
    for (int p = 0; p < 4; ++p) {
        int kk = (t >> 4) + p * 16;
        int nc = (t & 15) * 4;
        int k = bk + kk;
        float4 v = {0.f, 0.f, 0.f, 0.f};
        if (k < K && bn + nc + 3 < N)
            v = *(const float4*)&W[(size_t)k * N + bn + nc];
        tile[kk][nc] = v.x; tile[kk][nc + 1] = v.y;
        tile[kk][nc + 2] = v.z; tile[kk][nc + 3] = v.w;
    }
    __syncthreads();
    int nn = t >> 2;
    int kk0 = (t & 3) * 16;
    u16 hs[16], ls[16];
    #pragma unroll
    for (int j = 0; j < 16; ++j) split1(tile[kk0 + j][nn], hs[j], ls[j]);
    size_t ob = (size_t)(bn + nn) * Kp + bk + kk0;
    size_t lo = (size_t)Np * Kp;
    *(short8*)&Wt[ob] = *(short8*)hs;
    *(short8*)&Wt[ob + 8] = *(short8*)&hs[8];
    *(short8*)&Wt[lo + ob] = *(short8*)ls;
    *(short8*)&Wt[lo + ob + 8] = *(short8*)&ls[8];
}

__device__ void xsplit_dev(const float* __restrict__ x, u16* __restrict__ xs, int gblk) {
    int t = threadIdx.x;
    int r0 = gblk * 16 + (t >> 4);
    int l = t & 15;
    u16* xlo = xs + (size_t)MP * 512;
    #pragma unroll
    for (int j = 0; j < 8; ++j) {
        int k = (l + j * 16) * 4;
        float vals[4] = {0.f, 0.f, 0.f, 0.f};
        if (r0 < NN && k < 500) {
            float4 v = *(const float4*)&x[(size_t)r0 * 500 + k];
            vals[0] = v.x; vals[1] = v.y; vals[2] = v.z; vals[3] = v.w;
        }
        ushort4 hs, ls;
        split1(vals[0], hs.x, ls.x); split1(vals[1], hs.y, ls.y);
        split1(vals[2], hs.z, ls.z); split1(vals[3], hs.w, ls.w);
        *(ushort4*)&xs[(size_t)r0 * 512 + k] = hs;
        *(ushort4*)&xlo[(size_t)r0 * 512 + k] = ls;
    }
}

// ---------------- scatter + dedup degree + xsplit + weight splits --------------
// [0,1290): edges+diag scatter with first-set degree count;
// [1290,1922): xsplit; [1922,1954): W0; [1954,1956): fW1
__global__ __launch_bounds__(256)
void scatter_prep(const int* __restrict__ ei, unsigned int* __restrict__ bitmap,
                  float* __restrict__ deg, const float* __restrict__ x,
                  const float* __restrict__ W0, const float* __restrict__ fW1,
                  u16* __restrict__ xs, u16* __restrict__ W0t, u16* __restrict__ fW1t) {
    __shared__ char smem[16704];
    int b = blockIdx.x;
    if (b < 1290) {
        int e = b * 256 + threadIdx.x;
        if (e < NE + NN) {
            int i, j;
            if (e < NE) { i = ei[e]; j = ei[NE + e]; }
            else        { i = e - NE; j = i; }
            unsigned bit = 1u << (j & 31);
            unsigned old = atomicOr(&bitmap[i * ROW_WORDS + (j >> 5)], bit);
            if (!(old & bit)) atomicAdd(&deg[i], 1.0f);   // exactly-once per (i,j)
        }
    } else if (b < 1922) {
        xsplit_dev(x, xs, b - 1290);
    } else if (b < 1954) {
        int idx = b - 1922;
        splitW_dev(W0, 500, 256, 512, 256, W0t, idx & 7, idx >> 3, smem);
    } else {
        splitW_dev(fW1, 128, 40, 128, 64, fW1t, b - 1954, 0, smem);
    }
}

// ---------------- conv0 GEMM (r11 form; degree read directly, no popcount) -----
// H1 = deg ⊙ relu(deg*(x@W0) + b0); stats over relu output.
__global__ __launch_bounds__(256, 4)
void conv0_gemm(const u16* __restrict__ Ahi, const u16* __restrict__ Alo,
                const u16* __restrict__ Bhi, const u16* __restrict__ Blo,
                const float* __restrict__ deg, const float* __restrict__ bias,
                float* __restrict__ stats,
                u16* __restrict__ Ohi, u16* __restrict__ Olo) {
    __shared__ char smem[32768];   // Ahi|Alo|Bhi|Blo, 8 KB each
    __shared__ float sdeg[64];
    const int Kp = 512, M = NN, No = 256;
    const int b = blockIdx.x;
    const int xcd = b & 7, g = b >> 3;
    const int bx = g & 3, by = (g >> 2) * 8 + xcd;
    if (by >= 158) return;
    const int t = threadIdx.x;
    const int lane = t & 63;
    const int w = t >> 6;
    const int q = lane >> 4;
    const int l16 = lane & 15;
    const int m7 = l16 & 7;
    const int row0 = by * 64;
    const int col0 = bx * 64;

    const u16* bases[4] = {Ahi, Alo, Bhi, Blo};
    const u16* srcs[8];
    unsigned dstoff[8];
    #pragma unroll
    for (int i = 0; i < 8; ++i) {
        int gi = w + i * 4;
        int reg = i >> 1;
        int j = gi & 7;
        int rb = (reg < 2) ? row0 : col0;
        int r = j * 8 + (lane >> 3);
        int c = (lane & 7) ^ (r & 7);
        srcs[i] = bases[reg] + (size_t)(rb + r) * Kp + c * 8;
        dstoff[i] = reg * 8192 + j * 1024;
    }

    f32x4 acc[4];
    #pragma unroll
    for (int s = 0; s < 4; ++s) acc[s] = (f32x4){0.f, 0.f, 0.f, 0.f};

    #pragma unroll
    for (int i = 0; i < 8; ++i) { gll16(srcs[i], smem + dstoff[i]); srcs[i] += 64; }

    // degree prologue: one coalesced load; deg[] zero-padded past NN
    if (t < 64) sdeg[t] = deg[row0 + t];

    for (int k0 = 0; k0 < Kp; k0 += 64) {
        __syncthreads();
        short8 ah[2], al[2], bh[2][4], bl[2][4];
        #pragma unroll
        for (int kc = 0; kc < 2; ++kc) {
            int aoff = (w * 16 + l16) * 128 + (((kc * 4 + q) ^ m7) * 16);
            ah[kc] = *(const short8*)(smem + aoff);
            al[kc] = *(const short8*)(smem + 8192 + aoff);
            #pragma unroll
            for (int s = 0; s < 4; ++s) {
                int boff = (s * 16 + l16) * 128 + (((kc * 4 + q) ^ m7) * 16);
                bh[kc][s] = *(const short8*)(smem + 16384 + boff);
                bl[kc][s] = *(const short8*)(smem + 24576 + boff);
            }
        }
        __syncthreads();
        if (k0 + 64 < Kp) {
            #pragma unroll
            for (int i = 0; i < 8; ++i) { gll16(srcs[i], smem + dstoff[i]); srcs[i] += 64; }
        }
        #pragma unroll
        for (int kc = 0; kc < 2; ++kc)
            #pragma unroll
            for (int s = 0; s < 4; ++s) {
                acc[s] = __builtin_amdgcn_mfma_f32_16x16x32_bf16(al[kc], bh[kc][s], acc[s], 0, 0, 0);
                acc[s] = __builtin_amdgcn_mfma_f32_16x16x32_bf16(ah[kc], bl[kc][s], acc[s], 0, 0, 0);
                acc[s] = __builtin_amdgcn_mfma_f32_16x16x32_bf16(ah[kc], bh[kc][s], acc[s], 0, 0, 0);
            }
    }

    int growb = row0 + w * 16 + q * 4;
    float dgv[4];
    #pragma unroll
    for (int r = 0; r < 4; ++r) {
        int grow = growb + r;
        dgv[r] = (grow < M) ? sdeg[grow - row0] : 0.f;
    }
    #pragma unroll
    for (int s = 0; s < 4; ++s) {
        int gc = col0 + s * 16 + l16;
        float bia = bias[gc];
        float s_sum = 0.f, ss_sum = 0.f;
        #pragma unroll
        for (int r = 0; r < 4; ++r) {
            int grow = growb + r;
            bool real = grow < M;
            float v = fmaxf(fmaf(dgv[r], acc[s][r], bia), 0.f);
            if (!real) v = 0.f;
            s_sum += v; ss_sum += v * v;
            float vo = v * dgv[r];
            u16 h, l; split1(vo, h, l);
            Ohi[(size_t)grow * No + gc] = h;
            Olo[(size_t)grow * No + gc] = l;
        }
        s_sum  += __shfl_xor(s_sum, 16);  s_sum  += __shfl_xor(s_sum, 32);
        ss_sum += __shfl_xor(ss_sum, 16); ss_sum += __shfl_xor(ss_sum, 32);
        if (lane < 16) {
            atomicAdd(&stats[gc], s_sum);
            atomicAdd(&stats[256 + gc], ss_sum);
        }
    }
}

// ---------------- conv1 with in-kernel BN0 fold of W1 (proven r11) ----------------
__global__ __launch_bounds__(256, 4)
void conv1_fold(const u16* __restrict__ Ahi, const u16* __restrict__ Alo,
                const float* __restrict__ W1, const float* __restrict__ stats0,
                const float* __restrict__ g0, const float* __restrict__ bb0,
                const float* __restrict__ b1, const float* __restrict__ deg,
                float* __restrict__ stats1, u16* __restrict__ Ohi, u16* __restrict__ Olo) {
    __shared__ char smem[32768];
    __shared__ float scl[256], sh[256], cred[256], cvec[64];
    const int Kp = 256, M = NN, No = 256;
    const int b = blockIdx.x;
    const int xcd = b & 7, g = b >> 3;
    const int bx = g & 3, by = (g >> 2) * 8 + xcd;
    if (by >= 158) return;
    const int t = threadIdx.x;
    const int lane = t & 63;
    const int w = t >> 6;
    const int q = lane >> 4;
    const int l16 = lane & 15;
    const int m7 = l16 & 7;
    const int row0 = by * 64;
    const int col0 = bx * 64;

    const u16* srcs[4];
    unsigned dstoff[4];
    #pragma unroll
    for (int i = 0; i < 4; ++i) {
        int gi = w + i * 4;
        int plane = gi >> 3, j = gi & 7;
        int r = j * 8 + (lane >> 3);
        int c = (lane & 7) ^ (r & 7);
        srcs[i] = (plane ? Alo : Ahi) + (size_t)(row0 + r) * Kp + c * 8;
        dstoff[i] = plane * 8192 + j * 1024;
    }
    #pragma unroll
    for (int i = 0; i < 4; ++i) { gll16(srcs[i], smem + dstoff[i]); srcs[i] += 64; }

    {
        float mean = stats0[t] * (1.f / NN);
        float var = stats0[256 + t] * (1.f / NN) - mean * mean;
        float s = g0[t] * rsqrtf(var + BN_EPS);
        scl[t] = s;
        sh[t] = bb0[t] - mean * s;
    }
    __syncthreads();
    {
        float s = 0.f;
        int n = col0 + (t & 63);
        #pragma unroll 8
        for (int k = (t >> 6); k < 256; k += 4)
            s += sh[k] * W1[(size_t)k * 256 + n];
        cred[t] = s;
        __syncthreads();
        if (t < 64) cvec[t] = cred[t] + cred[t + 64] + cred[t + 128] + cred[t + 192];
    }
    const int bn = t & 63;
    const int kb = (t >> 6) * 16;
    const int ch0 = (t >> 6) * 2;
    float vals[16];
    {
        const float* wp = W1 + (size_t)kb * 256 + col0 + bn;
        #pragma unroll
        for (int i = 0; i < 16; ++i) vals[i] = wp[(size_t)i * 256] * scl[kb + i];
    }

    f32x4 acc[4];
    #pragma unroll
    for (int s = 0; s < 4; ++s) acc[s] = (f32x4){0.f, 0.f, 0.f, 0.f};

    for (int k0 = 0; k0 < Kp; k0 += 64) {
        {
            u16 hs[16], ls[16];
            #pragma unroll
            for (int i = 0; i < 16; ++i) split1(vals[i], hs[i], ls[i]);
            unsigned o0 = bn * 128 + ((ch0 ^ (bn & 7)) * 16);
            unsigned o1 = bn * 128 + (((ch0 + 1) ^ (bn & 7)) * 16);
            *(short8*)(smem + 16384 + o0) = *(short8*)&hs[0];
            *(short8*)(smem + 16384 + o1) = *(short8*)&hs[8];
            *(short8*)(smem + 24576 + o0) = *(short8*)&ls[0];
            *(short8*)(smem + 24576 + o1) = *(short8*)&ls[8];
        }
        __syncthreads();   // (1)
        short8 ah[2], al[2], bh[2][4], bl[2][4];
        #pragma unroll
        for (int kc = 0; kc < 2; ++kc) {
            int aoff = (w * 16 + l16) * 128 + (((kc * 4 + q) ^ m7) * 16);
            ah[kc] = *(const short8*)(smem + aoff);
            al[kc] = *(const short8*)(smem + 8192 + aoff);
            #pragma unroll
            for (int s = 0; s < 4; ++s) {
                int boff = (s * 16 + l16) * 128 + (((kc * 4 + q) ^ m7) * 16);
                bh[kc][s] = *(const short8*)(smem + 16384 + boff);
                bl[kc][s] = *(const short8*)(smem + 24576 + boff);
            }
        }
        __syncthreads();   // (2)
        if (k0 + 64 < Kp) {
            #pragma unroll
            for (int i = 0; i < 4; ++i) { gll16(srcs[i], smem + dstoff[i]); srcs[i] += 64; }
            const float* wp = W1 + (size_t)(k0 + 64 + kb) * 256 + col0 + bn;
            #pragma unroll
            for (int i = 0; i < 16; ++i) vals[i] = wp[(size_t)i * 256] * scl[k0 + 64 + kb + i];
        }
        #pragma unroll
        for (int kc = 0; kc < 2; ++kc)
            #pragma unroll
            for (int s = 0; s < 4; ++s) {
                acc[s] = __builtin_amdgcn_mfma_f32_16x16x32_bf16(al[kc], bh[kc][s], acc[s], 0, 0, 0);
                acc[s] = __builtin_amdgcn_mfma_f32_16x16x32_bf16(ah[kc], bl[kc][s], acc[s], 0, 0, 0);
                acc[s] = __builtin_amdgcn_mfma_f32_16x16x32_bf16(ah[kc], bh[kc][s], acc[s], 0, 0, 0);
            }
    }

    int growb = row0 + w * 16 + q * 4;
    float dgv[4];
    #pragma unroll
    for (int r = 0; r < 4; ++r) dgv[r] = (growb + r < M) ? deg[growb + r] : 0.f;
    #pragma unroll
    for (int s = 0; s < 4; ++s) {
        int gc = col0 + s * 16 + l16;
        float bia = b1[gc];
        float cv = cvec[s * 16 + l16];
        float s_sum = 0.f, ss_sum = 0.f;
        #pragma unroll
        for (int r = 0; r < 4; ++r) {
            int grow = growb + r;
            bool real = grow < M;
            float v = fmaxf(fmaf(dgv[r], cv, acc[s][r] + bia), 0.f);
            if (!real) v = 0.f;
            s_sum += v; ss_sum += v * v;
            u16 h, l; split1(v, h, l);
            Ohi[(size_t)grow * No + gc] = h;
            Olo[(size_t)grow * No + gc] = l;
        }
        s_sum  += __shfl_xor(s_sum, 16);  s_sum  += __shfl_xor(s_sum, 32);
        ss_sum += __shfl_xor(ss_sum, 16); ss_sum += __shfl_xor(ss_sum, 32);
        if (lane < 16) {
            atomicAdd(&stats1[gc], s_sum);
            atomicAdd(&stats1[256 + gc], ss_sum);
        }
    }
}

// ---------------- fused fc0 (BN1 fold, 64x128) + in-block fc1 ----------------
__global__ __launch_bounds__(256, 2)
void fc_fused(const u16* __restrict__ Ahi, const u16* __restrict__ Alo,
              const float* __restrict__ fW0, const float* __restrict__ stats1,
              const float* __restrict__ g1, const float* __restrict__ bb1,
              const float* __restrict__ fb0,
              const u16* __restrict__ Whi, const u16* __restrict__ Wlo,
              const float* __restrict__ fb1, float* __restrict__ out) {
    __shared__ char smem[49152];
    __shared__ float scl[256], sh[256], cred[256], biasf[128];
    const int M = NN;
    const int by = blockIdx.x;
    const int t = threadIdx.x;
    const int lane = t & 63;
    const int w = t >> 6;
    const int q = lane >> 4;
    const int l16 = lane & 15;
    const int m7 = l16 & 7;
    const int row0 = by * 64;

    const u16* asrc[4];
    unsigned adst[4];
    #pragma unroll
    for (int i = 0; i < 4; ++i) {
        int gi = w + i * 4;
        int plane = gi >> 3, j = gi & 7;
        int r = j * 8 + (lane >> 3);
        int c = (lane & 7) ^ (r & 7);
        asrc[i] = (plane ? Alo : Ahi) + (size_t)(row0 + r) * 256 + c * 8;
        adst[i] = plane * 8192 + j * 1024;
    }
    #pragma unroll
    for (int i = 0; i < 4; ++i) gll16(asrc[i], smem + adst[i]);   // sub0 k-step 0

    {
        float mean = stats1[t] * (1.f / NN);
        float var = stats1[256 + t] * (1.f / NN) - mean * mean;
        float s = g1[t] * rsqrtf(var + BN_EPS);
        scl[t] = s;
        sh[t] = bb1[t] - mean * s;
    }
    __syncthreads();
    {
        int col = t & 127, half = t >> 7;
        float s = 0.f;
        #pragma unroll 8
        for (int k = half * 128; k < half * 128 + 128; ++k)
            s += sh[k] * fW0[(size_t)k * 128 + col];
        cred[t] = s;
    }
    __syncthreads();
    if (t < 128) biasf[t] = fb0[t] + cred[t] + cred[128 + t];

    const int bn = t & 63;
    const int kb = (t >> 6) * 16;
    const int ch0 = (t >> 6) * 2;

    unsigned h3p[2][16];   // packed (hi<<16)|lo per relu output
    f32x4 acc[4];

    #pragma unroll
    for (int sub = 0; sub < 2; ++sub) {
        if (sub) {
            #pragma unroll
            for (int i = 0; i < 4; ++i) { asrc[i] -= 192; gll16(asrc[i], smem + adst[i]); }
        }
        float vals[16];
        {
            const float* wp = fW0 + (size_t)kb * 128 + sub * 64 + bn;
            #pragma unroll
            for (int i = 0; i < 16; ++i) vals[i] = wp[(size_t)i * 128] * scl[kb + i];
        }
        #pragma unroll
        for (int s = 0; s < 4; ++s) acc[s] = (f32x4){0.f, 0.f, 0.f, 0.f};

        for (int k0 = 0; k0 < 256; k0 += 64) {
            {
                u16 hs[16], ls[16];
                #pragma unroll
                for (int i = 0; i < 16; ++i) split1(vals[i], hs[i], ls[i]);
                unsigned o0 = bn * 128 + ((ch0 ^ (bn & 7)) * 16);
                unsigned o1 = bn * 128 + (((ch0 + 1) ^ (bn & 7)) * 16);
                *(short8*)(smem + 16384 + o0) = *(short8*)&hs[0];
                *(short8*)(smem + 16384 + o1) = *(short8*)&hs[8];
                *(short8*)(smem + 24576 + o0) = *(short8*)&ls[0];
                *(short8*)(smem + 24576 + o1) = *(short8*)&ls[8];
            }
            __syncthreads();   // (1)
            short8 ah[2], al[2], bh[2][4], bl[2][4];
            #pragma unroll
            for (int kc = 0; kc < 2; ++kc) {
                int aoff = (w * 16 + l16) * 128 + (((kc * 4 + q) ^ m7) * 16);
                ah[kc] = *(const short8*)(smem + aoff);
                al[kc] = *(const short8*)(smem + 8192 + aoff);
                #pragma unroll
                for (int s = 0; s < 4; ++s) {
                    int boff = (s * 16 + l16) * 128 + (((kc * 4 + q) ^ m7) * 16);
                    bh[kc][s] = *(const short8*)(smem + 16384 + boff);
                    bl[kc][s] = *(const short8*)(smem + 24576 + boff);
                }
            }
            __syncthreads();   // (2)
            if (k0 + 64 < 256) {
                #pragma unroll
                for (int i = 0; i < 4; ++i) { asrc[i] += 64; gll16(asrc[i], smem + adst[i]); }
                const float* wp = fW0 + (size_t)(k0 + 64 + kb) * 128 + sub * 64 + bn;
                #pragma unroll
                for (int i = 0; i < 16; ++i) vals[i] = wp[(size_t)i * 128] * scl[k0 + 64 + kb + i];
            }
            #pragma unroll
            for (int kc = 0; kc < 2; ++kc)
                #pragma unroll
                for (int s = 0; s < 4; ++s) {
                    acc[s] = __builtin_amdgcn_mfma_f32_16x16x32_bf16(al[kc], bh[kc][s], acc[s], 0, 0, 0);
                    acc[s] = __builtin_amdgcn_mfma_f32_16x16x32_bf16(ah[kc], bl[kc][s], acc[s], 0, 0, 0);
                    acc[s] = __builtin_amdgcn_mfma_f32_16x16x32_bf16(ah[kc], bh[kc][s], acc[s], 0, 0, 0);
                }
        }

        {
            int growb = row0 + w * 16 + q * 4;
            #pragma unroll
            for (int s = 0; s < 4; ++s) {
                float bia = biasf[sub * 64 + s * 16 + l16];
                #pragma unroll
                for (int r = 0; r < 4; ++r) {
                    float v = fmaxf(acc[s][r] + bia, 0.f);
                    if (growb + r >= M) v = 0.f;
                    u16 h, l; split1(v, h, l);
                    h3p[sub][s * 4 + r] = ((unsigned)h << 16) | l;
                }
            }
        }
    }

    // issue fc1 B staging, k-step 0 (region1 — untouched so far)
    #pragma unroll
    for (int i = 0; i < 4; ++i) {
        int gi = w + i * 4;
        int plane = gi >> 3, j = gi & 7;
        int r = j * 8 + (lane >> 3);
        int c = (lane & 7) ^ (r & 7);
        const u16* s = (plane ? Wlo : Whi) + (size_t)r * 128 + c * 8;
        gll16(s, smem + 32768 + plane * 8192 + j * 1024);
    }

    // write h3 into region0 in the fc1 A-frag layout
    {
        int rl0 = w * 16 + q * 4;
        #pragma unroll
        for (int sub = 0; sub < 2; ++sub)
            #pragma unroll
            for (int s = 0; s < 4; ++s)
                #pragma unroll
                for (int r = 0; r < 4; ++r) {
                    int rl = rl0 + r;
                    int kk = s * 16 + l16;            // k within step
                    int j = kk >> 3;
                    unsigned off = (unsigned)sub * 8192 + rl * 128 +
                                   ((j ^ (rl & 7)) * 16) + (kk & 7) * 2;
                    unsigned pv = h3p[sub][s * 4 + r];
                    *(u16*)(smem + off) = (u16)(pv >> 16);
                    *(u16*)(smem + 16384 + off) = (u16)pv;
                }
    }

    #pragma unroll
    for (int s = 0; s < 4; ++s) acc[s] = (f32x4){0.f, 0.f, 0.f, 0.f};

    __syncthreads();   // h3 visible; fc1 B st0 vmcnt drained

    #pragma unroll
    for (int st = 0; st < 2; ++st) {
        short8 ah[2], al[2], bh[2][4], bl[2][4];
        #pragma unroll
        for (int kc = 0; kc < 2; ++kc) {
            int aoff = st * 8192 + (w * 16 + l16) * 128 + (((kc * 4 + q) ^ m7) * 16);
            ah[kc] = *(const short8*)(smem + aoff);
            al[kc] = *(const short8*)(smem + 16384 + aoff);
            #pragma unroll
            for (int s = 0; s < 4; ++s) {
                int boff = 32768 + (s * 16 + l16) * 128 + (((kc * 4 + q) ^ m7) * 16);
                bh[kc][s] = *(const short8*)(smem + boff);
                bl[kc][s] = *(const short8*)(smem + 8192 + boff);
            }
        }
        __syncthreads();   // all reads of region1 done before restage
        if (st == 0) {
            #pragma unroll
            for (int i = 0; i < 4; ++i) {
                int gi = w + i * 4;
                int plane = gi >> 3, j = gi & 7;
                int r = j * 8 + (lane >> 3);
                int c = (lane & 7) ^ (r & 7);
                const u16* s = (plane ? Wlo : Whi) + (size_t)r * 128 + 64 + c * 8;
                gll16(s, smem + 32768 + plane * 8192 + j * 1024);
            }
        }
        #pragma unroll
        for (int kc = 0; kc < 2; ++kc)
            #pragma unroll
            for (int s = 0; s < 4; ++s) {
                acc[s] = __builtin_amdgcn_mfma_f32_16x16x32_bf16(al[kc], bh[kc][s], acc[s], 0, 0, 0);
                acc[s] = __builtin_amdgcn_mfma_f32_16x16x32_bf16(ah[kc], bl[kc][s], acc[s], 0, 0, 0);
                acc[s] = __builtin_amdgcn_mfma_f32_16x16x32_bf16(ah[kc], bh[kc][s], acc[s], 0, 0, 0);
            }
        if (st == 0) __syncthreads();   // fc1 B st1 ready
    }

    {
        int growb = row0 + w * 16 + q * 4;
        #pragma unroll
        for (int s = 0; s < 4; ++s) {
            int gc = s * 16 + l16;
            if (gc >= 40) continue;
            float bia = fb1[gc];
            #pragma unroll
            for (int r = 0; r < 4; ++r) {
                int grow = growb + r;
                if (grow < M)
                    out[(size_t)grow * 40 + gc] = fmaxf(acc[s][r] + bia, 0.f);
            }
        }
    }
}

// ---------------- launch ----------------

extern "C" void kernel_launch(void* const* d_in, const int* in_sizes, int n_in,
                              void* d_out, int out_size, void* d_ws, size_t ws_size,
                              hipStream_t stream) {
    const float* x   = (const float*)d_in[0];
    const int*   ei  = (const int*)d_in[1];
    const float* W0  = (const float*)d_in[2];
    const float* b0  = (const float*)d_in[3];
    const float* g0  = (const float*)d_in[4];
    const float* bb0 = (const float*)d_in[5];
    const float* W1  = (const float*)d_in[6];
    const float* b1  = (const float*)d_in[7];
    const float* g1  = (const float*)d_in[8];
    const float* bb1 = (const float*)d_in[9];
    const float* fW0 = (const float*)d_in[10];
    const float* fb0 = (const float*)d_in[11];
    const float* fW1 = (const float*)d_in[12];
    const float* fb1 = (const float*)d_in[13];
    float* out = (float*)d_out;

    char* ws = (char*)d_ws;
    auto carve = [&](size_t bytes) { char* q = ws; ws += (bytes + 255) & ~(size_t)255; return q; };

    const size_t BITMAP_BYTES = (size_t)NN * ROW_WORDS * 4;   // 12,800,000
    const size_t ZERO_BYTES = BITMAP_BYTES + 4096 + MP * 4;   // bitmap + stats + deg
    char* region0 = carve(ZERO_BYTES);
    unsigned int* bitmap = (unsigned int*)region0;
    float* stats = (float*)(region0 + BITMAP_BYTES);          // [0,512) conv0, [512,1024) conv1
    float* deg   = (float*)(region0 + BITMAP_BYTES + 4096);   // zeroed; padded rows read 0

    u16* xs     = (u16*)carve((size_t)2 * MP * 512 * 2);
    u16* W0t    = (u16*)carve((size_t)2 * 256 * 512 * 2);
    u16* fW1t   = (u16*)carve((size_t)2 * 64 * 128 * 2);
    u16* H1     = (u16*)carve((size_t)2 * MP * 256 * 2);
    u16* H2     = (u16*)carve((size_t)2 * MP * 256 * 2);

    dim3 blk(256);

    // 1. zero bitmap + stats + deg
    hipMemsetAsync(region0, 0, ZERO_BYTES, stream);
    // 2. scatter edges (with first-set degree count) + split x + split W0/fW1
    scatter_prep<<<1956, blk, 0, stream>>>(ei, bitmap, deg, x, W0, fW1, xs, W0t, fW1t);
    // 3. conv0 (degree read directly; no bitmap readback)
    conv0_gemm<<<640, blk, 0, stream>>>(
        xs, xs + (size_t)MP * 512, W0t, W0t + 256 * 512,
        deg, b0, stats, H1, H1 + (size_t)MP * 256);
    // 4. conv1 (self-folds BN0 into W1; swizzled)
    conv1_fold<<<640, blk, 0, stream>>>(
        H1, H1 + (size_t)MP * 256, W1, stats, g0, bb0, b1, deg,
        stats + 512, H2, H2 + (size_t)MP * 256);
    // 5. fused fc0+fc1 (H3 stays in LDS/registers)
    fc_fused<<<157, blk, 0, stream>>>(
        H2, H2 + (size_t)MP * 256, fW0, stats + 512, g1, bb1, fb0,
        fW1t, fW1t + 64 * 128, fb1, out);
}

// Round 3
// 197.130 us; speedup vs baseline: 1.0656x; 1.0656x over previous
//
#include <hip/hip_runtime.h>

#define NN 10000
#define NE 320000
#define ROW_WORDS 320   // 320*32 = 10240 bits >= 10000
#define MP 10112        // 158*64 padded rows
#define BN_EPS 1e-5f

#define NBUCK 64        // row-range buckets for edge scatter
#define BROWS 160       // rows per bucket (64*160 = 10240 >= NN)
#define BCAP  8192      // keys per bucket capacity (mean ~5000, sigma ~70)
#define EPB   5000      // edges per bucketize block (64*5000 = NE exact)

typedef __attribute__((ext_vector_type(8))) short short8;
typedef __attribute__((ext_vector_type(4))) float f32x4;
typedef unsigned short u16;

// ---------------- helpers ----------------
__device__ __forceinline__ void split1(float v, u16& h, u16& l) {
    unsigned int u = __float_as_uint(v);
    h = (u16)(u >> 16);
    float hf = __uint_as_float(u & 0xFFFF0000u);
    l = (u16)(__float_as_uint(v - hf) >> 16);
}

__device__ __forceinline__ void gll16(const void* g, void* l) {
    __builtin_amdgcn_global_load_lds(
        (const __attribute__((address_space(1))) unsigned int*)g,
        (__attribute__((address_space(3))) unsigned int*)l, 16, 0, 0);
}

// ---------------- splitW (proven): Wt[n][k] = split(W[k][n]) ----------------
__device__ void splitW_dev(const float* __restrict__ W, int K, int N, int Kp, int Np,
                           u16* __restrict__ Wt, int bx, int by, char* smem) {
    float (*tile)[65] = (float(*)[65])smem;
    int t = threadIdx.x;
    int bk = bx * 64, bn = by * 64;
    #pragma unroll
    for (int p = 0; p < 4; ++p) {
        int kk = (t >> 4) + p * 16;
        int nc = (t & 15) * 4;
        int k = bk + kk;
        float4 v = {0.f, 0.f, 0.f, 0.f};
        if (k < K && bn + nc + 3 < N)
            v = *(const float4*)&W[(size_t)k * N + bn + nc];
        tile[kk][nc] = v.x; tile[kk][nc + 1] = v.y;
        tile[kk][nc + 2] = v.z; tile[kk][nc + 3] = v.w;
    }
    __syncthreads();
    int nn = t >> 2;
    int kk0 = (t & 3) * 16;
    u16 hs[16], ls[16];
    #pragma unroll
    for (int j = 0; j < 16; ++j) split1(tile[kk0 + j][nn], hs[j], ls[j]);
    size_t ob = (size_t)(bn + nn) * Kp + bk + kk0;
    size_t lo = (size_t)Np * Kp;
    *(short8*)&Wt[ob] = *(short8*)hs;
    *(short8*)&Wt[ob + 8] = *(short8*)&hs[8];
    *(short8*)&Wt[lo + ob] = *(short8*)ls;
    *(short8*)&Wt[lo + ob + 8] = *(short8*)&ls[8];
}

__device__ void xsplit_dev(const float* __restrict__ x, u16* __restrict__ xs, int gblk) {
    int t = threadIdx.x;
    int r0 = gblk * 16 + (t >> 4);
    int l = t & 15;
    u16* xlo = xs + (size_t)MP * 512;
    #pragma unroll
    for (int j = 0; j < 8; ++j) {
        int k = (l + j * 16) * 4;
        float vals[4] = {0.f, 0.f, 0.f, 0.f};
        if (r0 < NN && k < 500) {
            float4 v = *(const float4*)&x[(size_t)r0 * 500 + k];
            vals[0] = v.x; vals[1] = v.y; vals[2] = v.z; vals[3] = v.w;
        }
        ushort4 hs, ls;
        split1(vals[0], hs.x, ls.x); split1(vals[1], hs.y, ls.y);
        split1(vals[2], hs.z, ls.z); split1(vals[3], hs.w, ls.w);
        *(ushort4*)&xs[(size_t)r0 * 512 + k] = hs;
        *(ushort4*)&xlo[(size_t)r0 * 512 + k] = ls;
    }
}

// ---------------- scatter_prep: bucketize + xsplit + weight splits --------------
// [0,64): edge bucketize (counting-sort into 64 row-range buckets);
// [64,696): xsplit; [696,728): W0; [728,730): fW1
__global__ __launch_bounds__(256)
void scatter_prep(const int* __restrict__ ei,
                  unsigned* __restrict__ bucketArr, unsigned* __restrict__ gcount,
                  const float* __restrict__ x,
                  const float* __restrict__ W0, const float* __restrict__ fW1,
                  u16* __restrict__ xs, u16* __restrict__ W0t, u16* __restrict__ fW1t) {
    __shared__ char smem[16704];
    __shared__ unsigned cnt[NBUCK], basep[NBUCK];
    int b = blockIdx.x;
    int t = threadIdx.x;
    if (b < 64) {
        if (t < NBUCK) cnt[t] = 0;
        __syncthreads();
        int base = b * EPB;
        unsigned myb[20], myk[20];
        #pragma unroll
        for (int k = 0; k < 20; ++k) {
            int el = t + k * 256;
            myb[k] = 0xFFFFFFFFu;
            if (el < EPB) {
                int e = base + el;
                unsigned i = (unsigned)ei[e], j = (unsigned)ei[NE + e];
                unsigned bk = i / BROWS;
                myb[k] = bk;
                myk[k] = (i << 14) | j;
                atomicAdd(&cnt[bk], 1u);
            }
        }
        __syncthreads();
        // reserve contiguous chunk per bucket (gcount padded 64B apart)
        if (t < NBUCK) { basep[t] = atomicAdd(&gcount[t * 16], cnt[t]); cnt[t] = 0; }
        __syncthreads();
        #pragma unroll
        for (int k = 0; k < 20; ++k) {
            if (myb[k] != 0xFFFFFFFFu) {
                unsigned bk = myb[k];
                unsigned pos = basep[bk] + atomicAdd(&cnt[bk], 1u);
                if (pos < BCAP) bucketArr[(size_t)bk * BCAP + pos] = myk[k];
            }
        }
    } else if (b < 696) {
        xsplit_dev(x, xs, b - 64);
    } else if (b < 728) {
        int idx = b - 696;
        splitW_dev(W0, 500, 256, 512, 256, W0t, idx & 7, idx >> 3, smem);
    } else {
        splitW_dev(fW1, 128, 40, 128, 64, fW1t, b - 728, 0, smem);
    }
}

// ---------------- bucket_scatter: per-bucket L2-local OR + popcount -> deg ------
// One block owns one bucket = 160 rows = 200 KB bitmap slice. All atomics from a
// single CU keep the slice resident in its XCD L2 (no cross-XCD RMW ping-pong).
// Popcount then reads the L2-hot slice and writes deg directly.
__global__ __launch_bounds__(256)
void bucket_scatter(const unsigned* __restrict__ bucketArr,
                    const unsigned* __restrict__ gcount,
                    unsigned* __restrict__ bitmap, float* __restrict__ deg) {
    int b = blockIdx.x, t = threadIdx.x;
    int row0 = b * BROWS;
    // diagonal bits (atomicOr: order-free wrt edge ORs)
    for (int r = t; r < BROWS; r += 256) {
        int grow = row0 + r;
        if (grow < NN)
            atomicOr(&bitmap[(size_t)grow * ROW_WORDS + (grow >> 5)], 1u << (grow & 31));
    }
    unsigned n = gcount[b * 16];
    const unsigned* keys = bucketArr + (size_t)b * BCAP;
    for (unsigned k = t; k < n; k += 256) {
        unsigned key = keys[k];
        unsigned i = key >> 14, j = key & 0x3FFFu;
        atomicOr(&bitmap[(size_t)i * ROW_WORDS + (j >> 5)], 1u << (j & 31));
    }
    __syncthreads();
    // popcount -> deg. Plain loads are safe: this block's only prior accesses to
    // the slice were atomics (L1-bypassing) and L1 is invalidated at dispatch
    // start, so loads miss L1 and read the L2-resident post-atomic data.
    #pragma unroll
    for (int pass = 0; pass < 3; ++pass) {
        int rr = pass * 64 + (t >> 2), wl = t & 3;
        if (rr >= BROWS) break;
        int grow = row0 + rr;
        int c = 0;
        if (grow < NN) {
            const uint4* rp = (const uint4*)(bitmap + (size_t)grow * ROW_WORDS) + wl;
            #pragma unroll
            for (int m = 0; m < 20; ++m) {
                uint4 v = rp[m * 4];
                c += __popc(v.x) + __popc(v.y) + __popc(v.z) + __popc(v.w);
            }
        }
        c += __shfl_down(c, 1, 4);
        c += __shfl_down(c, 2, 4);
        if (wl == 0 && grow < MP) deg[grow] = (float)c;
    }
}

// ---------------- conv0 GEMM (verified r2 form; degree read directly) ----------
// H1 = deg ⊙ relu(deg*(x@W0) + b0); stats over relu output.
__global__ __launch_bounds__(256, 4)
void conv0_gemm(const u16* __restrict__ Ahi, const u16* __restrict__ Alo,
                const u16* __restrict__ Bhi, const u16* __restrict__ Blo,
                const float* __restrict__ deg, const float* __restrict__ bias,
                float* __restrict__ stats,
                u16* __restrict__ Ohi, u16* __restrict__ Olo) {
    __shared__ char smem[32768];   // Ahi|Alo|Bhi|Blo, 8 KB each
    __shared__ float sdeg[64];
    const int Kp = 512, M = NN, No = 256;
    const int b = blockIdx.x;
    const int xcd = b & 7, g = b >> 3;
    const int bx = g & 3, by = (g >> 2) * 8 + xcd;
    if (by >= 158) return;
    const int t = threadIdx.x;
    const int lane = t & 63;
    const int w = t >> 6;
    const int q = lane >> 4;
    const int l16 = lane & 15;
    const int m7 = l16 & 7;
    const int row0 = by * 64;
    const int col0 = bx * 64;

    const u16* bases[4] = {Ahi, Alo, Bhi, Blo};
    const u16* srcs[8];
    unsigned dstoff[8];
    #pragma unroll
    for (int i = 0; i < 8; ++i) {
        int gi = w + i * 4;
        int reg = i >> 1;
        int j = gi & 7;
        int rb = (reg < 2) ? row0 : col0;
        int r = j * 8 + (lane >> 3);
        int c = (lane & 7) ^ (r & 7);
        srcs[i] = bases[reg] + (size_t)(rb + r) * Kp + c * 8;
        dstoff[i] = reg * 8192 + j * 1024;
    }

    f32x4 acc[4];
    #pragma unroll
    for (int s = 0; s < 4; ++s) acc[s] = (f32x4){0.f, 0.f, 0.f, 0.f};

    #pragma unroll
    for (int i = 0; i < 8; ++i) { gll16(srcs[i], smem + dstoff[i]); srcs[i] += 64; }

    // degree prologue: one coalesced load; deg[] fully written for rows < MP
    if (t < 64) sdeg[t] = deg[row0 + t];

    for (int k0 = 0; k0 < Kp; k0 += 64) {
        __syncthreads();
        short8 ah[2], al[2], bh[2][4], bl[2][4];
        #pragma unroll
        for (int kc = 0; kc < 2; ++kc) {
            int aoff = (w * 16 + l16) * 128 + (((kc * 4 + q) ^ m7) * 16);
            ah[kc] = *(const short8*)(smem + aoff);
            al[kc] = *(const short8*)(smem + 8192 + aoff);
            #pragma unroll
            for (int s = 0; s < 4; ++s) {
                int boff = (s * 16 + l16) * 128 + (((kc * 4 + q) ^ m7) * 16);
                bh[kc][s] = *(const short8*)(smem + 16384 + boff);
                bl[kc][s] = *(const short8*)(smem + 24576 + boff);
            }
        }
        __syncthreads();
        if (k0 + 64 < Kp) {
            #pragma unroll
            for (int i = 0; i < 8; ++i) { gll16(srcs[i], smem + dstoff[i]); srcs[i] += 64; }
        }
        #pragma unroll
        for (int kc = 0; kc < 2; ++kc)
            #pragma unroll
            for (int s = 0; s < 4; ++s) {
                acc[s] = __builtin_amdgcn_mfma_f32_16x16x32_bf16(al[kc], bh[kc][s], acc[s], 0, 0, 0);
                acc[s] = __builtin_amdgcn_mfma_f32_16x16x32_bf16(ah[kc], bl[kc][s], acc[s], 0, 0, 0);
                acc[s] = __builtin_amdgcn_mfma_f32_16x16x32_bf16(ah[kc], bh[kc][s], acc[s], 0, 0, 0);
            }
    }

    int growb = row0 + w * 16 + q * 4;
    float dgv[4];
    #pragma unroll
    for (int r = 0; r < 4; ++r) {
        int grow = growb + r;
        dgv[r] = (grow < M) ? sdeg[grow - row0] : 0.f;
    }
    #pragma unroll
    for (int s = 0; s < 4; ++s) {
        int gc = col0 + s * 16 + l16;
        float bia = bias[gc];
        float s_sum = 0.f, ss_sum = 0.f;
        #pragma unroll
        for (int r = 0; r < 4; ++r) {
            int grow = growb + r;
            bool real = grow < M;
            float v = fmaxf(fmaf(dgv[r], acc[s][r], bia), 0.f);
            if (!real) v = 0.f;
            s_sum += v; ss_sum += v * v;
            float vo = v * dgv[r];
            u16 h, l; split1(vo, h, l);
            Ohi[(size_t)grow * No + gc] = h;
            Olo[(size_t)grow * No + gc] = l;
        }
        s_sum  += __shfl_xor(s_sum, 16);  s_sum  += __shfl_xor(s_sum, 32);
        ss_sum += __shfl_xor(ss_sum, 16); ss_sum += __shfl_xor(ss_sum, 32);
        if (lane < 16) {
            atomicAdd(&stats[gc], s_sum);
            atomicAdd(&stats[256 + gc], ss_sum);
        }
    }
}

// ---------------- conv1 with in-kernel BN0 fold of W1 (proven r11) ----------------
__global__ __launch_bounds__(256, 4)
void conv1_fold(const u16* __restrict__ Ahi, const u16* __restrict__ Alo,
                const float* __restrict__ W1, const float* __restrict__ stats0,
                const float* __restrict__ g0, const float* __restrict__ bb0,
                const float* __restrict__ b1, const float* __restrict__ deg,
                float* __restrict__ stats1, u16* __restrict__ Ohi, u16* __restrict__ Olo) {
    __shared__ char smem[32768];
    __shared__ float scl[256], sh[256], cred[256], cvec[64];
    const int Kp = 256, M = NN, No = 256;
    const int b = blockIdx.x;
    const int xcd = b & 7, g = b >> 3;
    const int bx = g & 3, by = (g >> 2) * 8 + xcd;
    if (by >= 158) return;
    const int t = threadIdx.x;
    const int lane = t & 63;
    const int w = t >> 6;
    const int q = lane >> 4;
    const int l16 = lane & 15;
    const int m7 = l16 & 7;
    const int row0 = by * 64;
    const int col0 = bx * 64;

    const u16* srcs[4];
    unsigned dstoff[4];
    #pragma unroll
    for (int i = 0; i < 4; ++i) {
        int gi = w + i * 4;
        int plane = gi >> 3, j = gi & 7;
        int r = j * 8 + (lane >> 3);
        int c = (lane & 7) ^ (r & 7);
        srcs[i] = (plane ? Alo : Ahi) + (size_t)(row0 + r) * Kp + c * 8;
        dstoff[i] = plane * 8192 + j * 1024;
    }
    #pragma unroll
    for (int i = 0; i < 4; ++i) { gll16(srcs[i], smem + dstoff[i]); srcs[i] += 64; }

    {
        float mean = stats0[t] * (1.f / NN);
        float var = stats0[256 + t] * (1.f / NN) - mean * mean;
        float s = g0[t] * rsqrtf(var + BN_EPS);
        scl[t] = s;
        sh[t] = bb0[t] - mean * s;
    }
    __syncthreads();
    {
        float s = 0.f;
        int n = col0 + (t & 63);
        #pragma unroll 8
        for (int k = (t >> 6); k < 256; k += 4)
            s += sh[k] * W1[(size_t)k * 256 + n];
        cred[t] = s;
        __syncthreads();
        if (t < 64) cvec[t] = cred[t] + cred[t + 64] + cred[t + 128] + cred[t + 192];
    }
    const int bn = t & 63;
    const int kb = (t >> 6) * 16;
    const int ch0 = (t >> 6) * 2;
    float vals[16];
    {
        const float* wp = W1 + (size_t)kb * 256 + col0 + bn;
        #pragma unroll
        for (int i = 0; i < 16; ++i) vals[i] = wp[(size_t)i * 256] * scl[kb + i];
    }

    f32x4 acc[4];
    #pragma unroll
    for (int s = 0; s < 4; ++s) acc[s] = (f32x4){0.f, 0.f, 0.f, 0.f};

    for (int k0 = 0; k0 < Kp; k0 += 64) {
        {
            u16 hs[16], ls[16];
            #pragma unroll
            for (int i = 0; i < 16; ++i) split1(vals[i], hs[i], ls[i]);
            unsigned o0 = bn * 128 + ((ch0 ^ (bn & 7)) * 16);
            unsigned o1 = bn * 128 + (((ch0 + 1) ^ (bn & 7)) * 16);
            *(short8*)(smem + 16384 + o0) = *(short8*)&hs[0];
            *(short8*)(smem + 16384 + o1) = *(short8*)&hs[8];
            *(short8*)(smem + 24576 + o0) = *(short8*)&ls[0];
            *(short8*)(smem + 24576 + o1) = *(short8*)&ls[8];
        }
        __syncthreads();   // (1)
        short8 ah[2], al[2], bh[2][4], bl[2][4];
        #pragma unroll
        for (int kc = 0; kc < 2; ++kc) {
            int aoff = (w * 16 + l16) * 128 + (((kc * 4 + q) ^ m7) * 16);
            ah[kc] = *(const short8*)(smem + aoff);
            al[kc] = *(const short8*)(smem + 8192 + aoff);
            #pragma unroll
            for (int s = 0; s < 4; ++s) {
                int boff = (s * 16 + l16) * 128 + (((kc * 4 + q) ^ m7) * 16);
                bh[kc][s] = *(const short8*)(smem + 16384 + boff);
                bl[kc][s] = *(const short8*)(smem + 24576 + boff);
            }
        }
        __syncthreads();   // (2)
        if (k0 + 64 < Kp) {
            #pragma unroll
            for (int i = 0; i < 4; ++i) { gll16(srcs[i], smem + dstoff[i]); srcs[i] += 64; }
            const float* wp = W1 + (size_t)(k0 + 64 + kb) * 256 + col0 + bn;
            #pragma unroll
            for (int i = 0; i < 16; ++i) vals[i] = wp[(size_t)i * 256] * scl[k0 + 64 + kb + i];
        }
        #pragma unroll
        for (int kc = 0; kc < 2; ++kc)
            #pragma unroll
            for (int s = 0; s < 4; ++s) {
                acc[s] = __builtin_amdgcn_mfma_f32_16x16x32_bf16(al[kc], bh[kc][s], acc[s], 0, 0, 0);
                acc[s] = __builtin_amdgcn_mfma_f32_16x16x32_bf16(ah[kc], bl[kc][s], acc[s], 0, 0, 0);
                acc[s] = __builtin_amdgcn_mfma_f32_16x16x32_bf16(ah[kc], bh[kc][s], acc[s], 0, 0, 0);
            }
    }

    int growb = row0 + w * 16 + q * 4;
    float dgv[4];
    #pragma unroll
    for (int r = 0; r < 4; ++r) dgv[r] = (growb + r < M) ? deg[growb + r] : 0.f;
    #pragma unroll
    for (int s = 0; s < 4; ++s) {
        int gc = col0 + s * 16 + l16;
        float bia = b1[gc];
        float cv = cvec[s * 16 + l16];
        float s_sum = 0.f, ss_sum = 0.f;
        #pragma unroll
        for (int r = 0; r < 4; ++r) {
            int grow = growb + r;
            bool real = grow < M;
            float v = fmaxf(fmaf(dgv[r], cv, acc[s][r] + bia), 0.f);
            if (!real) v = 0.f;
            s_sum += v; ss_sum += v * v;
            u16 h, l; split1(v, h, l);
            Ohi[(size_t)grow * No + gc] = h;
            Olo[(size_t)grow * No + gc] = l;
        }
        s_sum  += __shfl_xor(s_sum, 16);  s_sum  += __shfl_xor(s_sum, 32);
        ss_sum += __shfl_xor(ss_sum, 16); ss_sum += __shfl_xor(ss_sum, 32);
        if (lane < 16) {
            atomicAdd(&stats1[gc], s_sum);
            atomicAdd(&stats1[256 + gc], ss_sum);
        }
    }
}

// ---------------- fused fc0 (BN1 fold, 64x128) + in-block fc1 ----------------
__global__ __launch_bounds__(256, 2)
void fc_fused(const u16* __restrict__ Ahi, const u16* __restrict__ Alo,
              const float* __restrict__ fW0, const float* __restrict__ stats1,
              const float* __restrict__ g1, const float* __restrict__ bb1,
              const float* __restrict__ fb0,
              const u16* __restrict__ Whi, const u16* __restrict__ Wlo,
              const float* __restrict__ fb1, float* __restrict__ out) {
    __shared__ char smem[49152];
    __shared__ float scl[256], sh[256], cred[256], biasf[128];
    const int M = NN;
    const int by = blockIdx.x;
    const int t = threadIdx.x;
    const int lane = t & 63;
    const int w = t >> 6;
    const int q = lane >> 4;
    const int l16 = lane & 15;
    const int m7 = l16 & 7;
    const int row0 = by * 64;

    const u16* asrc[4];
    unsigned adst[4];
    #pragma unroll
    for (int i = 0; i < 4; ++i) {
        int gi = w + i * 4;
        int plane = gi >> 3, j = gi & 7;
        int r = j * 8 + (lane >> 3);
        int c = (lane & 7) ^ (r & 7);
        asrc[i] = (plane ? Alo : Ahi) + (size_t)(row0 + r) * 256 + c * 8;
        adst[i] = plane * 8192 + j * 1024;
    }
    #pragma unroll
    for (int i = 0; i < 4; ++i) gll16(asrc[i], smem + adst[i]);   // sub0 k-step 0

    {
        float mean = stats1[t] * (1.f / NN);
        float var = stats1[256 + t] * (1.f / NN) - mean * mean;
        float s = g1[t] * rsqrtf(var + BN_EPS);
        scl[t] = s;
        sh[t] = bb1[t] - mean * s;
    }
    __syncthreads();
    {
        int col = t & 127, half = t >> 7;
        float s = 0.f;
        #pragma unroll 8
        for (int k = half * 128; k < half * 128 + 128; ++k)
            s += sh[k] * fW0[(size_t)k * 128 + col];
        cred[t] = s;
    }
    __syncthreads();
    if (t < 128) biasf[t] = fb0[t] + cred[t] + cred[128 + t];

    const int bn = t & 63;
    const int kb = (t >> 6) * 16;
    const int ch0 = (t >> 6) * 2;

    unsigned h3p[2][16];   // packed (hi<<16)|lo per relu output
    f32x4 acc[4];

    #pragma unroll
    for (int sub = 0; sub < 2; ++sub) {
        if (sub) {
            #pragma unroll
            for (int i = 0; i < 4; ++i) { asrc[i] -= 192; gll16(asrc[i], smem + adst[i]); }
        }
        float vals[16];
        {
            const float* wp = fW0 + (size_t)kb * 128 + sub * 64 + bn;
            #pragma unroll
            for (int i = 0; i < 16; ++i) vals[i] = wp[(size_t)i * 128] * scl[kb + i];
        }
        #pragma unroll
        for (int s = 0; s < 4; ++s) acc[s] = (f32x4){0.f, 0.f, 0.f, 0.f};

        for (int k0 = 0; k0 < 256; k0 += 64) {
            {
                u16 hs[16], ls[16];
                #pragma unroll
                for (int i = 0; i < 16; ++i) split1(vals[i], hs[i], ls[i]);
                unsigned o0 = bn * 128 + ((ch0 ^ (bn & 7)) * 16);
                unsigned o1 = bn * 128 + (((ch0 + 1) ^ (bn & 7)) * 16);
                *(short8*)(smem + 16384 + o0) = *(short8*)&hs[0];
                *(short8*)(smem + 16384 + o1) = *(short8*)&hs[8];
                *(short8*)(smem + 24576 + o0) = *(short8*)&ls[0];
                *(short8*)(smem + 24576 + o1) = *(short8*)&ls[8];
            }
            __syncthreads();   // (1)
            short8 ah[2], al[2], bh[2][4], bl[2][4];
            #pragma unroll
            for (int kc = 0; kc < 2; ++kc) {
                int aoff = (w * 16 + l16) * 128 + (((kc * 4 + q) ^ m7) * 16);
                ah[kc] = *(const short8*)(smem + aoff);
                al[kc] = *(const short8*)(smem + 8192 + aoff);
                #pragma unroll
                for (int s = 0; s < 4; ++s) {
                    int boff = (s * 16 + l16) * 128 + (((kc * 4 + q) ^ m7) * 16);
                    bh[kc][s] = *(const short8*)(smem + 16384 + boff);
                    bl[kc][s] = *(const short8*)(smem + 24576 + boff);
                }
            }
            __syncthreads();   // (2)
            if (k0 + 64 < 256) {
                #pragma unroll
                for (int i = 0; i < 4; ++i) { asrc[i] += 64; gll16(asrc[i], smem + adst[i]); }
                const float* wp = fW0 + (size_t)(k0 + 64 + kb) * 128 + sub * 64 + bn;
                #pragma unroll
                for (int i = 0; i < 16; ++i) vals[i] = wp[(size_t)i * 128] * scl[k0 + 64 + kb + i];
            }
            #pragma unroll
            for (int kc = 0; kc < 2; ++kc)
                #pragma unroll
                for (int s = 0; s < 4; ++s) {
                    acc[s] = __builtin_amdgcn_mfma_f32_16x16x32_bf16(al[kc], bh[kc][s], acc[s], 0, 0, 0);
                    acc[s] = __builtin_amdgcn_mfma_f32_16x16x32_bf16(ah[kc], bl[kc][s], acc[s], 0, 0, 0);
                    acc[s] = __builtin_amdgcn_mfma_f32_16x16x32_bf16(ah[kc], bh[kc][s], acc[s], 0, 0, 0);
                }
        }

        {
            int growb = row0 + w * 16 + q * 4;
            #pragma unroll
            for (int s = 0; s < 4; ++s) {
                float bia = biasf[sub * 64 + s * 16 + l16];
                #pragma unroll
                for (int r = 0; r < 4; ++r) {
                    float v = fmaxf(acc[s][r] + bia, 0.f);
                    if (growb + r >= M) v = 0.f;
                    u16 h, l; split1(v, h, l);
                    h3p[sub][s * 4 + r] = ((unsigned)h << 16) | l;
                }
            }
        }
    }

    // issue fc1 B staging, k-step 0 (region1 — untouched so far)
    #pragma unroll
    for (int i = 0; i < 4; ++i) {
        int gi = w + i * 4;
        int plane = gi >> 3, j = gi & 7;
        int r = j * 8 + (lane >> 3);
        int c = (lane & 7) ^ (r & 7);
        const u16* s = (plane ? Wlo : Whi) + (size_t)r * 128 + c * 8;
        gll16(s, smem + 32768 + plane * 8192 + j * 1024);
    }

    // write h3 into region0 in the fc1 A-frag layout
    {
        int rl0 = w * 16 + q * 4;
        #pragma unroll
        for (int sub = 0; sub < 2; ++sub)
            #pragma unroll
            for (int s = 0; s < 4; ++s)
                #pragma unroll
                for (int r = 0; r < 4; ++r) {
                    int rl = rl0 + r;
                    int kk = s * 16 + l16;            // k within step
                    int j = kk >> 3;
                    unsigned off = (unsigned)sub * 8192 + rl * 128 +
                                   ((j ^ (rl & 7)) * 16) + (kk & 7) * 2;
                    unsigned pv = h3p[sub][s * 4 + r];
                    *(u16*)(smem + off) = (u16)(pv >> 16);
                    *(u16*)(smem + 16384 + off) = (u16)pv;
                }
    }

    #pragma unroll
    for (int s = 0; s < 4; ++s) acc[s] = (f32x4){0.f, 0.f, 0.f, 0.f};

    __syncthreads();   // h3 visible; fc1 B st0 vmcnt drained

    #pragma unroll
    for (int st = 0; st < 2; ++st) {
        short8 ah[2], al[2], bh[2][4], bl[2][4];
        #pragma unroll
        for (int kc = 0; kc < 2; ++kc) {
            int aoff = st * 8192 + (w * 16 + l16) * 128 + (((kc * 4 + q) ^ m7) * 16);
            ah[kc] = *(const short8*)(smem + aoff);
            al[kc] = *(const short8*)(smem + 16384 + aoff);
            #pragma unroll
            for (int s = 0; s < 4; ++s) {
                int boff = 32768 + (s * 16 + l16) * 128 + (((kc * 4 + q) ^ m7) * 16);
                bh[kc][s] = *(const short8*)(smem + boff);
                bl[kc][s] = *(const short8*)(smem + 8192 + boff);
            }
        }
        __syncthreads();   // all reads of region1 done before restage
        if (st == 0) {
            #pragma unroll
            for (int i = 0; i < 4; ++i) {
                int gi = w + i * 4;
                int plane = gi >> 3, j = gi & 7;
                int r = j * 8 + (lane >> 3);
                int c = (lane & 7) ^ (r & 7);
                const u16* s = (plane ? Wlo : Whi) + (size_t)r * 128 + 64 + c * 8;
                gll16(s, smem + 32768 + plane * 8192 + j * 1024);
            }
        }
        #pragma unroll
        for (int kc = 0; kc < 2; ++kc)
            #pragma unroll
            for (int s = 0; s < 4; ++s) {
                acc[s] = __builtin_amdgcn_mfma_f32_16x16x32_bf16(al[kc], bh[kc][s], acc[s], 0, 0, 0);
                acc[s] = __builtin_amdgcn_mfma_f32_16x16x32_bf16(ah[kc], bl[kc][s], acc[s], 0, 0, 0);
                acc[s] = __builtin_amdgcn_mfma_f32_16x16x32_bf16(ah[kc], bh[kc][s], acc[s], 0, 0, 0);
            }
        if (st == 0) __syncthreads();   // fc1 B st1 ready
    }

    {
        int growb = row0 + w * 16 + q * 4;
        #pragma unroll
        for (int s = 0; s < 4; ++s) {
            int gc = s * 16 + l16;
            if (gc >= 40) continue;
            float bia = fb1[gc];
            #pragma unroll
            for (int r = 0; r < 4; ++r) {
                int grow = growb + r;
                if (grow < M)
                    out[(size_t)grow * 40 + gc] = fmaxf(acc[s][r] + bia, 0.f);
            }
        }
    }
}

// ---------------- launch ----------------

extern "C" void kernel_launch(void* const* d_in, const int* in_sizes, int n_in,
                              void* d_out, int out_size, void* d_ws, size_t ws_size,
                              hipStream_t stream) {
    const float* x   = (const float*)d_in[0];
    const int*   ei  = (const int*)d_in[1];
    const float* W0  = (const float*)d_in[2];
    const float* b0  = (const float*)d_in[3];
    const float* g0  = (const float*)d_in[4];
    const float* bb0 = (const float*)d_in[5];
    const float* W1  = (const float*)d_in[6];
    const float* b1  = (const float*)d_in[7];
    const float* g1  = (const float*)d_in[8];
    const float* bb1 = (const float*)d_in[9];
    const float* fW0 = (const float*)d_in[10];
    const float* fb0 = (const float*)d_in[11];
    const float* fW1 = (const float*)d_in[12];
    const float* fb1 = (const float*)d_in[13];
    float* out = (float*)d_out;

    char* ws = (char*)d_ws;
    auto carve = [&](size_t bytes) { char* q = ws; ws += (bytes + 255) & ~(size_t)255; return q; };

    const size_t BITMAP_BYTES = (size_t)NN * ROW_WORDS * 4;   // 12,800,000
    const size_t GCOUNT_BYTES = (size_t)NBUCK * 16 * 4;       // padded counters
    const size_t ZERO_BYTES = BITMAP_BYTES + 4096 + GCOUNT_BYTES;
    char* region0 = carve(ZERO_BYTES);
    unsigned int* bitmap = (unsigned int*)region0;
    float* stats = (float*)(region0 + BITMAP_BYTES);          // [0,512) conv0, [512,1024) conv1
    unsigned* gcount = (unsigned*)(region0 + BITMAP_BYTES + 4096);

    float* deg       = (float*)carve(MP * 4);                 // fully written by bucket_scatter
    unsigned* bucketArr = (unsigned*)carve((size_t)NBUCK * BCAP * 4);   // 2 MB
    u16* xs     = (u16*)carve((size_t)2 * MP * 512 * 2);
    u16* W0t    = (u16*)carve((size_t)2 * 256 * 512 * 2);
    u16* fW1t   = (u16*)carve((size_t)2 * 64 * 128 * 2);
    u16* H1     = (u16*)carve((size_t)2 * MP * 256 * 2);
    u16* H2     = (u16*)carve((size_t)2 * MP * 256 * 2);

    dim3 blk(256);

    // 1. zero bitmap + stats + gcount
    hipMemsetAsync(region0, 0, ZERO_BYTES, stream);
    // 2. bucketize edges + split x + split W0/fW1 (one dispatch)
    scatter_prep<<<730, blk, 0, stream>>>(ei, bucketArr, gcount, x, W0, fW1, xs, W0t, fW1t);
    // 3. per-bucket L2-local scatter + popcount -> deg
    bucket_scatter<<<NBUCK, blk, 0, stream>>>(bucketArr, gcount, bitmap, deg);
    // 4. conv0 (degree read directly; no bitmap readback)
    conv0_gemm<<<640, blk, 0, stream>>>(
        xs, xs + (size_t)MP * 512, W0t, W0t + 256 * 512,
        deg, b0, stats, H1, H1 + (size_t)MP * 256);
    // 5. conv1 (self-folds BN0 into W1; swizzled)
    conv1_fold<<<640, blk, 0, stream>>>(
        H1, H1 + (size_t)MP * 256, W1, stats, g0, bb0, b1, deg,
        stats + 512, H2, H2 + (size_t)MP * 256);
    // 6. fused fc0+fc1 (H3 stays in LDS/registers)
    fc_fused<<<157, blk, 0, stream>>>(
        H2, H2 + (size_t)MP * 256, fW0, stats + 512, g1, bb1, fb0,
        fW1t, fW1t + 64 * 128, fb1, out);
}

// Round 4
// 179.895 us; speedup vs baseline: 1.1677x; 1.0958x over previous
//
#include <hip/hip_runtime.h>

#define NN 10000
#define NE 320000
#define MP 10112        // 158*64 padded rows
#define BN_EPS 1e-5f

#define NRANGE 64       // row-ranges (160 rows each)
#define BROWS 160
#define NBUCK 128       // row-range x j-half buckets
#define HBITS 5120      // bits per j-half
#define HWORDS 160      // words per j-half row
#define BCAP  4096      // keys per bucket capacity (mean ~2500)
#define EPB   5000      // edges per bucketize block (64*5000 = NE exact)

typedef __attribute__((ext_vector_type(8))) short short8;
typedef __attribute__((ext_vector_type(4))) float f32x4;
typedef unsigned short u16;

// ---------------- helpers ----------------
__device__ __forceinline__ void split1(float v, u16& h, u16& l) {
    unsigned int u = __float_as_uint(v);
    h = (u16)(u >> 16);
    float hf = __uint_as_float(u & 0xFFFF0000u);
    l = (u16)(__float_as_uint(v - hf) >> 16);
}

__device__ __forceinline__ void gll16(const void* g, void* l) {
    __builtin_amdgcn_global_load_lds(
        (const __attribute__((address_space(1))) unsigned int*)g,
        (__attribute__((address_space(3))) unsigned int*)l, 16, 0, 0);
}

// ---------------- splitW (proven): Wt[n][k] = split(W[k][n]) ----------------
__device__ void splitW_dev(const float* __restrict__ W, int K, int N, int Kp, int Np,
                           u16* __restrict__ Wt, int bx, int by, char* smem) {
    float (*tile)[65] = (float(*)[65])smem;
    int t = threadIdx.x;
    int bk = bx * 64, bn = by * 64;
    #pragma unroll
    for (int p = 0; p < 4; ++p) {
        int kk = (t >> 4) + p * 16;
        int nc = (t & 15) * 4;
        int k = bk + kk;
        float4 v = {0.f, 0.f, 0.f, 0.f};
        if (k < K && bn + nc + 3 < N)
            v = *(const float4*)&W[(size_t)k * N + bn + nc];
        tile[kk][nc] = v.x; tile[kk][nc + 1] = v.y;
        tile[kk][nc + 2] = v.z; tile[kk][nc + 3] = v.w;
    }
    __syncthreads();
    int nn = t >> 2;
    int kk0 = (t & 3) * 16;
    u16 hs[16], ls[16];
    #pragma unroll
    for (int j = 0; j < 16; ++j) split1(tile[kk0 + j][nn], hs[j], ls[j]);
    size_t ob = (size_t)(bn + nn) * Kp + bk + kk0;
    size_t lo = (size_t)Np * Kp;
    *(short8*)&Wt[ob] = *(short8*)hs;
    *(short8*)&Wt[ob + 8] = *(short8*)&hs[8];
    *(short8*)&Wt[lo + ob] = *(short8*)ls;
    *(short8*)&Wt[lo + ob + 8] = *(short8*)&ls[8];
}

__device__ void xsplit_dev(const float* __restrict__ x, u16* __restrict__ xs, int gblk) {
    int t = threadIdx.x;
    int r0 = gblk * 16 + (t >> 4);
    int l = t & 15;
    u16* xlo = xs + (size_t)MP * 512;
    #pragma unroll
    for (int j = 0; j < 8; ++j) {
        int k = (l + j * 16) * 4;
        float vals[4] = {0.f, 0.f, 0.f, 0.f};
        if (r0 < NN && k < 500) {
            float4 v = *(const float4*)&x[(size_t)r0 * 500 + k];
            vals[0] = v.x; vals[1] = v.y; vals[2] = v.z; vals[3] = v.w;
        }
        ushort4 hs, ls;
        split1(vals[0], hs.x, ls.x); split1(vals[1], hs.y, ls.y);
        split1(vals[2], hs.z, ls.z); split1(vals[3], hs.w, ls.w);
        *(ushort4*)&xs[(size_t)r0 * 512 + k] = hs;
        *(ushort4*)&xlo[(size_t)r0 * 512 + k] = ls;
    }
}

// ---------------- scatter_prep: bucketize + xsplit + weight splits --------------
// [0,64): edge bucketize into 128 (row-range, j-half) buckets;
// [64,696): xsplit; [696,728): W0; [728,730): fW1
__global__ __launch_bounds__(256)
void scatter_prep(const int* __restrict__ ei,
                  unsigned* __restrict__ bucketArr, unsigned* __restrict__ gcount,
                  const float* __restrict__ x,
                  const float* __restrict__ W0, const float* __restrict__ fW1,
                  u16* __restrict__ xs, u16* __restrict__ W0t, u16* __restrict__ fW1t) {
    __shared__ char smem[16704];
    __shared__ unsigned cnt[NBUCK], basep[NBUCK];
    int b = blockIdx.x;
    int t = threadIdx.x;
    if (b < 64) {
        if (t < NBUCK) cnt[t] = 0;
        __syncthreads();
        int base = b * EPB;
        unsigned myb[20], myk[20];
        #pragma unroll
        for (int k = 0; k < 20; ++k) {
            int el = t + k * 256;
            myb[k] = 0xFFFFFFFFu;
            if (el < EPB) {
                int e = base + el;
                unsigned i = (unsigned)ei[e], j = (unsigned)ei[NE + e];
                unsigned bk = (i / BROWS) * 2 + (j >= HBITS ? 1u : 0u);
                myb[k] = bk;
                myk[k] = (i << 14) | j;
                atomicAdd(&cnt[bk], 1u);
            }
        }
        __syncthreads();
        // reserve contiguous chunk per bucket (gcount padded 64B apart)
        if (t < NBUCK) { basep[t] = atomicAdd(&gcount[t * 16], cnt[t]); cnt[t] = 0; }
        __syncthreads();
        #pragma unroll
        for (int k = 0; k < 20; ++k) {
            if (myb[k] != 0xFFFFFFFFu) {
                unsigned bk = myb[k];
                unsigned pos = basep[bk] + atomicAdd(&cnt[bk], 1u);
                if (pos < BCAP) bucketArr[(size_t)bk * BCAP + pos] = myk[k];
            }
        }
    } else if (b < 696) {
        xsplit_dev(x, xs, b - 64);
    } else if (b < 728) {
        int idx = b - 696;
        splitW_dev(W0, 500, 256, 512, 256, W0t, idx & 7, idx >> 3, smem);
    } else {
        splitW_dev(fW1, 128, 40, 128, 64, fW1t, b - 728, 0, smem);
    }
}

// ---------------- bucket_degree: LDS-bitmap dedup + popcount -> deg ------------
// One block owns (row-range of 160 rows) x (one j-half of 5120 bits):
// a 100 KB LDS bitmap. LDS atomicOr dedups; popcount adds the half-row count
// into deg (two half-blocks per row sum to the full dedup degree). No global
// bitmap exists at all.
__global__ __launch_bounds__(256)
void bucket_degree(const unsigned* __restrict__ bucketArr,
                   const unsigned* __restrict__ gcount,
                   float* __restrict__ deg) {
    __shared__ unsigned lbm[BROWS * HWORDS];   // 102,400 B
    int b = blockIdx.x, t = threadIdx.x;
    int rr = b >> 1, h = b & 1;
    int row0 = rr * BROWS;
    {
        uint4* z = (uint4*)lbm;
        #pragma unroll
        for (int i = 0; i < 25; ++i) z[t + i * 256] = (uint4){0u, 0u, 0u, 0u};
    }
    __syncthreads();
    // diagonal bit for rows whose j=i falls in this half
    for (int r = t; r < BROWS; r += 256) {
        int i = row0 + r;
        if (i < NN && ((i >= HBITS) == (h == 1))) {
            int jj = i - h * HBITS;
            atomicOr(&lbm[r * HWORDS + (jj >> 5)], 1u << (jj & 31));
        }
    }
    unsigned n = gcount[b * 16];
    const unsigned* keys = bucketArr + (size_t)b * BCAP;
    for (unsigned k = t; k < n; k += 256) {
        unsigned key = keys[k];
        unsigned i = key >> 14, j = key & 0x3FFFu;
        unsigned r = i - row0;
        unsigned jj = j - h * HBITS;
        atomicOr(&lbm[r * HWORDS + (jj >> 5)], 1u << (jj & 31));
    }
    __syncthreads();
    // popcount: 4 threads/row, 40 words each (uint4 x10)
    #pragma unroll
    for (int pass = 0; pass < 3; ++pass) {
        int r = pass * 64 + (t >> 2), wl = t & 3;
        if (r >= BROWS) break;
        int i = row0 + r;
        int c = 0;
        const uint4* rp = (const uint4*)&lbm[r * HWORDS + wl * 40];
        #pragma unroll
        for (int m = 0; m < 10; ++m) {
            uint4 v = rp[m];
            c += __popc(v.x) + __popc(v.y) + __popc(v.z) + __popc(v.w);
        }
        c += __shfl_down(c, 1, 4);
        c += __shfl_down(c, 2, 4);
        if (wl == 0 && i < NN) atomicAdd(&deg[i], (float)c);
    }
}

// ---------------- conv0 GEMM (verified r3 form; degree read directly) ----------
// H1 = deg ⊙ relu(deg*(x@W0) + b0); stats over relu output.
__global__ __launch_bounds__(256, 4)
void conv0_gemm(const u16* __restrict__ Ahi, const u16* __restrict__ Alo,
                const u16* __restrict__ Bhi, const u16* __restrict__ Blo,
                const float* __restrict__ deg, const float* __restrict__ bias,
                float* __restrict__ stats,
                u16* __restrict__ Ohi, u16* __restrict__ Olo) {
    __shared__ char smem[32768];   // Ahi|Alo|Bhi|Blo, 8 KB each
    __shared__ float sdeg[64];
    const int Kp = 512, M = NN, No = 256;
    const int b = blockIdx.x;
    const int xcd = b & 7, g = b >> 3;
    const int bx = g & 3, by = (g >> 2) * 8 + xcd;
    if (by >= 158) return;
    const int t = threadIdx.x;
    const int lane = t & 63;
    const int w = t >> 6;
    const int q = lane >> 4;
    const int l16 = lane & 15;
    const int m7 = l16 & 7;
    const int row0 = by * 64;
    const int col0 = bx * 64;

    const u16* bases[4] = {Ahi, Alo, Bhi, Blo};
    const u16* srcs[8];
    unsigned dstoff[8];
    #pragma unroll
    for (int i = 0; i < 8; ++i) {
        int gi = w + i * 4;
        int reg = i >> 1;
        int j = gi & 7;
        int rb = (reg < 2) ? row0 : col0;
        int r = j * 8 + (lane >> 3);
        int c = (lane & 7) ^ (r & 7);
        srcs[i] = bases[reg] + (size_t)(rb + r) * Kp + c * 8;
        dstoff[i] = reg * 8192 + j * 1024;
    }

    f32x4 acc[4];
    #pragma unroll
    for (int s = 0; s < 4; ++s) acc[s] = (f32x4){0.f, 0.f, 0.f, 0.f};

    #pragma unroll
    for (int i = 0; i < 8; ++i) { gll16(srcs[i], smem + dstoff[i]); srcs[i] += 64; }

    // degree prologue: one coalesced load; deg[] zeroed past NN
    if (t < 64) sdeg[t] = deg[row0 + t];

    for (int k0 = 0; k0 < Kp; k0 += 64) {
        __syncthreads();
        short8 ah[2], al[2], bh[2][4], bl[2][4];
        #pragma unroll
        for (int kc = 0; kc < 2; ++kc) {
            int aoff = (w * 16 + l16) * 128 + (((kc * 4 + q) ^ m7) * 16);
            ah[kc] = *(const short8*)(smem + aoff);
            al[kc] = *(const short8*)(smem + 8192 + aoff);
            #pragma unroll
            for (int s = 0; s < 4; ++s) {
                int boff = (s * 16 + l16) * 128 + (((kc * 4 + q) ^ m7) * 16);
                bh[kc][s] = *(const short8*)(smem + 16384 + boff);
                bl[kc][s] = *(const short8*)(smem + 24576 + boff);
            }
        }
        __syncthreads();
        if (k0 + 64 < Kp) {
            #pragma unroll
            for (int i = 0; i < 8; ++i) { gll16(srcs[i], smem + dstoff[i]); srcs[i] += 64; }
        }
        #pragma unroll
        for (int kc = 0; kc < 2; ++kc)
            #pragma unroll
            for (int s = 0; s < 4; ++s) {
                acc[s] = __builtin_amdgcn_mfma_f32_16x16x32_bf16(al[kc], bh[kc][s], acc[s], 0, 0, 0);
                acc[s] = __builtin_amdgcn_mfma_f32_16x16x32_bf16(ah[kc], bl[kc][s], acc[s], 0, 0, 0);
                acc[s] = __builtin_amdgcn_mfma_f32_16x16x32_bf16(ah[kc], bh[kc][s], acc[s], 0, 0, 0);
            }
    }

    int growb = row0 + w * 16 + q * 4;
    float dgv[4];
    #pragma unroll
    for (int r = 0; r < 4; ++r) {
        int grow = growb + r;
        dgv[r] = (grow < M) ? sdeg[grow - row0] : 0.f;
    }
    #pragma unroll
    for (int s = 0; s < 4; ++s) {
        int gc = col0 + s * 16 + l16;
        float bia = bias[gc];
        float s_sum = 0.f, ss_sum = 0.f;
        #pragma unroll
        for (int r = 0; r < 4; ++r) {
            int grow = growb + r;
            bool real = grow < M;
            float v = fmaxf(fmaf(dgv[r], acc[s][r], bia), 0.f);
            if (!real) v = 0.f;
            s_sum += v; ss_sum += v * v;
            float vo = v * dgv[r];
            u16 h, l; split1(vo, h, l);
            Ohi[(size_t)grow * No + gc] = h;
            Olo[(size_t)grow * No + gc] = l;
        }
        s_sum  += __shfl_xor(s_sum, 16);  s_sum  += __shfl_xor(s_sum, 32);
        ss_sum += __shfl_xor(ss_sum, 16); ss_sum += __shfl_xor(ss_sum, 32);
        if (lane < 16) {
            atomicAdd(&stats[gc], s_sum);
            atomicAdd(&stats[256 + gc], ss_sum);
        }
    }
}

// ---------------- conv1 with in-kernel BN0 fold of W1 (proven r11) ----------------
__global__ __launch_bounds__(256, 4)
void conv1_fold(const u16* __restrict__ Ahi, const u16* __restrict__ Alo,
                const float* __restrict__ W1, const float* __restrict__ stats0,
                const float* __restrict__ g0, const float* __restrict__ bb0,
                const float* __restrict__ b1, const float* __restrict__ deg,
                float* __restrict__ stats1, u16* __restrict__ Ohi, u16* __restrict__ Olo) {
    __shared__ char smem[32768];
    __shared__ float scl[256], sh[256], cred[256], cvec[64];
    const int Kp = 256, M = NN, No = 256;
    const int b = blockIdx.x;
    const int xcd = b & 7, g = b >> 3;
    const int bx = g & 3, by = (g >> 2) * 8 + xcd;
    if (by >= 158) return;
    const int t = threadIdx.x;
    const int lane = t & 63;
    const int w = t >> 6;
    const int q = lane >> 4;
    const int l16 = lane & 15;
    const int m7 = l16 & 7;
    const int row0 = by * 64;
    const int col0 = bx * 64;

    const u16* srcs[4];
    unsigned dstoff[4];
    #pragma unroll
    for (int i = 0; i < 4; ++i) {
        int gi = w + i * 4;
        int plane = gi >> 3, j = gi & 7;
        int r = j * 8 + (lane >> 3);
        int c = (lane & 7) ^ (r & 7);
        srcs[i] = (plane ? Alo : Ahi) + (size_t)(row0 + r) * Kp + c * 8;
        dstoff[i] = plane * 8192 + j * 1024;
    }
    #pragma unroll
    for (int i = 0; i < 4; ++i) { gll16(srcs[i], smem + dstoff[i]); srcs[i] += 64; }

    {
        float mean = stats0[t] * (1.f / NN);
        float var = stats0[256 + t] * (1.f / NN) - mean * mean;
        float s = g0[t] * rsqrtf(var + BN_EPS);
        scl[t] = s;
        sh[t] = bb0[t] - mean * s;
    }
    __syncthreads();
    {
        float s = 0.f;
        int n = col0 + (t & 63);
        #pragma unroll 8
        for (int k = (t >> 6); k < 256; k += 4)
            s += sh[k] * W1[(size_t)k * 256 + n];
        cred[t] = s;
        __syncthreads();
        if (t < 64) cvec[t] = cred[t] + cred[t + 64] + cred[t + 128] + cred[t + 192];
    }
    const int bn = t & 63;
    const int kb = (t >> 6) * 16;
    const int ch0 = (t >> 6) * 2;
    float vals[16];
    {
        const float* wp = W1 + (size_t)kb * 256 + col0 + bn;
        #pragma unroll
        for (int i = 0; i < 16; ++i) vals[i] = wp[(size_t)i * 256] * scl[kb + i];
    }

    f32x4 acc[4];
    #pragma unroll
    for (int s = 0; s < 4; ++s) acc[s] = (f32x4){0.f, 0.f, 0.f, 0.f};

    for (int k0 = 0; k0 < Kp; k0 += 64) {
        {
            u16 hs[16], ls[16];
            #pragma unroll
            for (int i = 0; i < 16; ++i) split1(vals[i], hs[i], ls[i]);
            unsigned o0 = bn * 128 + ((ch0 ^ (bn & 7)) * 16);
            unsigned o1 = bn * 128 + (((ch0 + 1) ^ (bn & 7)) * 16);
            *(short8*)(smem + 16384 + o0) = *(short8*)&hs[0];
            *(short8*)(smem + 16384 + o1) = *(short8*)&hs[8];
            *(short8*)(smem + 24576 + o0) = *(short8*)&ls[0];
            *(short8*)(smem + 24576 + o1) = *(short8*)&ls[8];
        }
        __syncthreads();   // (1)
        short8 ah[2], al[2], bh[2][4], bl[2][4];
        #pragma unroll
        for (int kc = 0; kc < 2; ++kc) {
            int aoff = (w * 16 + l16) * 128 + (((kc * 4 + q) ^ m7) * 16);
            ah[kc] = *(const short8*)(smem + aoff);
            al[kc] = *(const short8*)(smem + 8192 + aoff);
            #pragma unroll
            for (int s = 0; s < 4; ++s) {
                int boff = (s * 16 + l16) * 128 + (((kc * 4 + q) ^ m7) * 16);
                bh[kc][s] = *(const short8*)(smem + 16384 + boff);
                bl[kc][s] = *(const short8*)(smem + 24576 + boff);
            }
        }
        __syncthreads();   // (2)
        if (k0 + 64 < Kp) {
            #pragma unroll
            for (int i = 0; i < 4; ++i) { gll16(srcs[i], smem + dstoff[i]); srcs[i] += 64; }
            const float* wp = W1 + (size_t)(k0 + 64 + kb) * 256 + col0 + bn;
            #pragma unroll
            for (int i = 0; i < 16; ++i) vals[i] = wp[(size_t)i * 256] * scl[k0 + 64 + kb + i];
        }
        #pragma unroll
        for (int kc = 0; kc < 2; ++kc)
            #pragma unroll
            for (int s = 0; s < 4; ++s) {
                acc[s] = __builtin_amdgcn_mfma_f32_16x16x32_bf16(al[kc], bh[kc][s], acc[s], 0, 0, 0);
                acc[s] = __builtin_amdgcn_mfma_f32_16x16x32_bf16(ah[kc], bl[kc][s], acc[s], 0, 0, 0);
                acc[s] = __builtin_amdgcn_mfma_f32_16x16x32_bf16(ah[kc], bh[kc][s], acc[s], 0, 0, 0);
            }
    }

    int growb = row0 + w * 16 + q * 4;
    float dgv[4];
    #pragma unroll
    for (int r = 0; r < 4; ++r) dgv[r] = (growb + r < M) ? deg[growb + r] : 0.f;
    #pragma unroll
    for (int s = 0; s < 4; ++s) {
        int gc = col0 + s * 16 + l16;
        float bia = b1[gc];
        float cv = cvec[s * 16 + l16];
        float s_sum = 0.f, ss_sum = 0.f;
        #pragma unroll
        for (int r = 0; r < 4; ++r) {
            int grow = growb + r;
            bool real = grow < M;
            float v = fmaxf(fmaf(dgv[r], cv, acc[s][r] + bia), 0.f);
            if (!real) v = 0.f;
            s_sum += v; ss_sum += v * v;
            u16 h, l; split1(v, h, l);
            Ohi[(size_t)grow * No + gc] = h;
            Olo[(size_t)grow * No + gc] = l;
        }
        s_sum  += __shfl_xor(s_sum, 16);  s_sum  += __shfl_xor(s_sum, 32);
        ss_sum += __shfl_xor(ss_sum, 16); ss_sum += __shfl_xor(ss_sum, 32);
        if (lane < 16) {
            atomicAdd(&stats1[gc], s_sum);
            atomicAdd(&stats1[256 + gc], ss_sum);
        }
    }
}

// ---------------- fc0 with in-kernel BN1 fold of fW0 (proven r11) ----------------
__global__ __launch_bounds__(256, 4)
void fc0_fold(const u16* __restrict__ Ahi, const u16* __restrict__ Alo,
              const float* __restrict__ fW0, const float* __restrict__ stats1,
              const float* __restrict__ g1, const float* __restrict__ bb1,
              const float* __restrict__ fb0,
              u16* __restrict__ Ohi, u16* __restrict__ Olo) {
    __shared__ char smem[32768];
    __shared__ float scl[256], sh[256], cred[256], biasf[64];
    const int Kp = 256, M = NN, No = 128;
    const int b = blockIdx.x;
    const int xcd = b & 7, g = b >> 3;
    const int bx = g & 1, by = (g >> 1) * 8 + xcd;
    if (by >= 158) return;
    const int t = threadIdx.x;
    const int lane = t & 63;
    const int w = t >> 6;
    const int q = lane >> 4;
    const int l16 = lane & 15;
    const int m7 = l16 & 7;
    const int row0 = by * 64;
    const int col0 = bx * 64;

    const u16* srcs[4];
    unsigned dstoff[4];
    #pragma unroll
    for (int i = 0; i < 4; ++i) {
        int gi = w + i * 4;
        int plane = gi >> 3, j = gi & 7;
        int r = j * 8 + (lane >> 3);
        int c = (lane & 7) ^ (r & 7);
        srcs[i] = (plane ? Alo : Ahi) + (size_t)(row0 + r) * Kp + c * 8;
        dstoff[i] = plane * 8192 + j * 1024;
    }
    #pragma unroll
    for (int i = 0; i < 4; ++i) { gll16(srcs[i], smem + dstoff[i]); srcs[i] += 64; }

    {
        float mean = stats1[t] * (1.f / NN);
        float var = stats1[256 + t] * (1.f / NN) - mean * mean;
        float s = g1[t] * rsqrtf(var + BN_EPS);
        scl[t] = s;
        sh[t] = bb1[t] - mean * s;
    }
    __syncthreads();
    {
        float s = 0.f;
        int n = col0 + (t & 63);
        #pragma unroll 8
        for (int k = (t >> 6); k < 256; k += 4)
            s += sh[k] * fW0[(size_t)k * 128 + n];
        cred[t] = s;
        __syncthreads();
        if (t < 64)
            biasf[t] = fb0[col0 + t] + cred[t] + cred[t + 64] + cred[t + 128] + cred[t + 192];
    }
    const int bn = t & 63;
    const int kb = (t >> 6) * 16;
    const int ch0 = (t >> 6) * 2;
    float vals[16];
    {
        const float* wp = fW0 + (size_t)kb * 128 + col0 + bn;
        #pragma unroll
        for (int i = 0; i < 16; ++i) vals[i] = wp[(size_t)i * 128] * scl[kb + i];
    }

    f32x4 acc[4];
    #pragma unroll
    for (int s = 0; s < 4; ++s) acc[s] = (f32x4){0.f, 0.f, 0.f, 0.f};

    for (int k0 = 0; k0 < Kp; k0 += 64) {
        {
            u16 hs[16], ls[16];
            #pragma unroll
            for (int i = 0; i < 16; ++i) split1(vals[i], hs[i], ls[i]);
            unsigned o0 = bn * 128 + ((ch0 ^ (bn & 7)) * 16);
            unsigned o1 = bn * 128 + (((ch0 + 1) ^ (bn & 7)) * 16);
            *(short8*)(smem + 16384 + o0) = *(short8*)&hs[0];
            *(short8*)(smem + 16384 + o1) = *(short8*)&hs[8];
            *(short8*)(smem + 24576 + o0) = *(short8*)&ls[0];
            *(short8*)(smem + 24576 + o1) = *(short8*)&ls[8];
        }
        __syncthreads();   // (1)
        short8 ah[2], al[2], bh[2][4], bl[2][4];
        #pragma unroll
        for (int kc = 0; kc < 2; ++kc) {
            int aoff = (w * 16 + l16) * 128 + (((kc * 4 + q) ^ m7) * 16);
            ah[kc] = *(const short8*)(smem + aoff);
            al[kc] = *(const short8*)(smem + 8192 + aoff);
            #pragma unroll
            for (int s = 0; s < 4; ++s) {
                int boff = (s * 16 + l16) * 128 + (((kc * 4 + q) ^ m7) * 16);
                bh[kc][s] = *(const short8*)(smem + 16384 + boff);
                bl[kc][s] = *(const short8*)(smem + 24576 + boff);
            }
        }
        __syncthreads();   // (2)
        if (k0 + 64 < Kp) {
            #pragma unroll
            for (int i = 0; i < 4; ++i) { gll16(srcs[i], smem + dstoff[i]); srcs[i] += 64; }
            const float* wp = fW0 + (size_t)(k0 + 64 + kb) * 128 + col0 + bn;
            #pragma unroll
            for (int i = 0; i < 16; ++i) vals[i] = wp[(size_t)i * 128] * scl[k0 + 64 + kb + i];
        }
        #pragma unroll
        for (int kc = 0; kc < 2; ++kc)
            #pragma unroll
            for (int s = 0; s < 4; ++s) {
                acc[s] = __builtin_amdgcn_mfma_f32_16x16x32_bf16(al[kc], bh[kc][s], acc[s], 0, 0, 0);
                acc[s] = __builtin_amdgcn_mfma_f32_16x16x32_bf16(ah[kc], bl[kc][s], acc[s], 0, 0, 0);
                acc[s] = __builtin_amdgcn_mfma_f32_16x16x32_bf16(ah[kc], bh[kc][s], acc[s], 0, 0, 0);
            }
    }

    int growb = row0 + w * 16 + q * 4;
    #pragma unroll
    for (int s = 0; s < 4; ++s) {
        int gc = col0 + s * 16 + l16;
        float bia = biasf[s * 16 + l16];
        #pragma unroll
        for (int r = 0; r < 4; ++r) {
            int grow = growb + r;
            float v = fmaxf(acc[s][r] + bia, 0.f);
            if (grow >= M) v = 0.f;
            u16 h, l; split1(v, h, l);
            Ohi[(size_t)grow * No + gc] = h;
            Olo[(size_t)grow * No + gc] = l;
        }
    }
}

// ---------------- fc1 (proven): Kp=128, N=40, fp32 out ----------------
__global__ __launch_bounds__(256, 3)
void fc1_gemm(const u16* __restrict__ Ahi, const u16* __restrict__ Alo,
              const u16* __restrict__ Bhi, const u16* __restrict__ Blo,
              const float* __restrict__ bias, float* __restrict__ out) {
    __shared__ char smem[32768];
    const int Kp = 128, M = NN, N = 40, No = 40;
    const int t = threadIdx.x;
    const int lane = t & 63;
    const int w = t >> 6;
    const int q = lane >> 4;
    const int l16 = lane & 15;
    const int m7 = l16 & 7;
    const int row0 = blockIdx.x * 64;
    const int col0 = 0;

    const u16* bases[4] = {Ahi, Alo, Bhi, Blo};
    const u16* srcs[8];
    unsigned dstoff[8];
    #pragma unroll
    for (int i = 0; i < 8; ++i) {
        int gi = w + i * 4;
        int reg = i >> 1;
        int j = gi & 7;
        int rb = (reg < 2) ? row0 : col0;
        int r = j * 8 + (lane >> 3);
        int c = (lane & 7) ^ (r & 7);
        srcs[i] = bases[reg] + (size_t)(rb + r) * Kp + c * 8;
        dstoff[i] = reg * 8192 + j * 1024;
    }

    f32x4 acc[4];
    #pragma unroll
    for (int s = 0; s < 4; ++s) acc[s] = (f32x4){0.f, 0.f, 0.f, 0.f};

    #pragma unroll
    for (int i = 0; i < 8; ++i) { gll16(srcs[i], smem + dstoff[i]); srcs[i] += 64; }

    for (int k0 = 0; k0 < Kp; k0 += 64) {
        __syncthreads();
        short8 ah[2], al[2], bh[2][4], bl[2][4];
        #pragma unroll
        for (int kc = 0; kc < 2; ++kc) {
            int aoff = (w * 16 + l16) * 128 + (((kc * 4 + q) ^ m7) * 16);
            ah[kc] = *(const short8*)(smem + aoff);
            al[kc] = *(const short8*)(smem + 8192 + aoff);
            #pragma unroll
            for (int s = 0; s < 4; ++s) {
                int boff = (s * 16 + l16) * 128 + (((kc * 4 + q) ^ m7) * 16);
                bh[kc][s] = *(const short8*)(smem + 16384 + boff);
                bl[kc][s] = *(const short8*)(smem + 24576 + boff);
            }
        }
        __syncthreads();
        if (k0 + 64 < Kp) {
            #pragma unroll
            for (int i = 0; i < 8; ++i) { gll16(srcs[i], smem + dstoff[i]); srcs[i] += 64; }
        }
        #pragma unroll
        for (int kc = 0; kc < 2; ++kc)
            #pragma unroll
            for (int s = 0; s < 4; ++s) {
                acc[s] = __builtin_amdgcn_mfma_f32_16x16x32_bf16(al[kc], bh[kc][s], acc[s], 0, 0, 0);
                acc[s] = __builtin_amdgcn_mfma_f32_16x16x32_bf16(ah[kc], bl[kc][s], acc[s], 0, 0, 0);
                acc[s] = __builtin_amdgcn_mfma_f32_16x16x32_bf16(ah[kc], bh[kc][s], acc[s], 0, 0, 0);
            }
    }

    int growb = row0 + w * 16 + q * 4;
    #pragma unroll
    for (int s = 0; s < 4; ++s) {
        int gc = col0 + s * 16 + l16;
        if (gc >= N) continue;
        float bia = bias[gc];
        #pragma unroll
        for (int r = 0; r < 4; ++r) {
            int grow = growb + r;
            if (grow < M)
                out[(size_t)grow * No + gc] = fmaxf(acc[s][r] + bia, 0.f);
        }
    }
}

// ---------------- launch ----------------

extern "C" void kernel_launch(void* const* d_in, const int* in_sizes, int n_in,
                              void* d_out, int out_size, void* d_ws, size_t ws_size,
                              hipStream_t stream) {
    const float* x   = (const float*)d_in[0];
    const int*   ei  = (const int*)d_in[1];
    const float* W0  = (const float*)d_in[2];
    const float* b0  = (const float*)d_in[3];
    const float* g0  = (const float*)d_in[4];
    const float* bb0 = (const float*)d_in[5];
    const float* W1  = (const float*)d_in[6];
    const float* b1  = (const float*)d_in[7];
    const float* g1  = (const float*)d_in[8];
    const float* bb1 = (const float*)d_in[9];
    const float* fW0 = (const float*)d_in[10];
    const float* fb0 = (const float*)d_in[11];
    const float* fW1 = (const float*)d_in[12];
    const float* fb1 = (const float*)d_in[13];
    float* out = (float*)d_out;

    char* ws = (char*)d_ws;
    auto carve = [&](size_t bytes) { char* q = ws; ws += (bytes + 255) & ~(size_t)255; return q; };

    // small zeroed region: stats (4KB) + gcount (8KB) + deg (MP*4)
    const size_t ZERO_BYTES = 4096 + 8192 + (size_t)MP * 4;
    char* region0 = carve(ZERO_BYTES);
    float* stats = (float*)region0;                         // [0,512) conv0, [512,1024) conv1
    unsigned* gcount = (unsigned*)(region0 + 4096);         // padded counters, 128 x 64B
    float* deg   = (float*)(region0 + 4096 + 8192);         // accumulated by bucket_degree

    unsigned* bucketArr = (unsigned*)carve((size_t)NBUCK * BCAP * 4);   // 2 MB
    u16* xs     = (u16*)carve((size_t)2 * MP * 512 * 2);
    u16* W0t    = (u16*)carve((size_t)2 * 256 * 512 * 2);
    u16* fW1t   = (u16*)carve((size_t)2 * 64 * 128 * 2);
    u16* H1     = (u16*)carve((size_t)2 * MP * 256 * 2);
    u16* H2     = (u16*)carve((size_t)2 * MP * 256 * 2);
    u16* H3     = (u16*)carve((size_t)2 * MP * 128 * 2);

    dim3 blk(256);

    // 1. zero stats + gcount + deg (53 KB — no 12.8 MB bitmap anymore)
    hipMemsetAsync(region0, 0, ZERO_BYTES, stream);
    // 2. bucketize edges + split x + split W0/fW1 (one dispatch)
    scatter_prep<<<730, blk, 0, stream>>>(ei, bucketArr, gcount, x, W0, fW1, xs, W0t, fW1t);
    // 3. LDS-bitmap dedup + popcount -> deg (no global bitmap)
    bucket_degree<<<NBUCK, blk, 0, stream>>>(bucketArr, gcount, deg);
    // 4. conv0 (degree read directly)
    conv0_gemm<<<640, blk, 0, stream>>>(
        xs, xs + (size_t)MP * 512, W0t, W0t + 256 * 512,
        deg, b0, stats, H1, H1 + (size_t)MP * 256);
    // 5. conv1 (self-folds BN0 into W1; swizzled)
    conv1_fold<<<640, blk, 0, stream>>>(
        H1, H1 + (size_t)MP * 256, W1, stats, g0, bb0, b1, deg,
        stats + 512, H2, H2 + (size_t)MP * 256);
    // 6. fc0 (self-folds BN1 into fW0; swizzled)
    fc0_fold<<<320, blk, 0, stream>>>(
        H2, H2 + (size_t)MP * 256, fW0, stats + 512, g1, bb1, fb0,
        H3, H3 + (size_t)MP * 128);
    // 7. fc1
    fc1_gemm<<<158, blk, 0, stream>>>(
        H3, H3 + (size_t)MP * 128, fW1t, fW1t + 64 * 128, fb1, out);
}